// Round 8
// baseline (1595.263 us; speedup 1.0000x reference)
//
#include <hip/hip_runtime.h>
#include <hip/hip_bf16.h>
#include <stdint.h>

// Problem constants (fixed by reference)
#define BATCH 16
#define NPTS  8192
#define NCH   6
#define NGRP  512   // NUM_GROUPS (FPS samples)
#define GSZ   32    // GROUP_SIZE (kNN)

#define TPB    1024            // threads per block (both roles)
#define FPPT   8               // fps: contiguous mapping, idx = tid*8 + j
#define KPPT   8               // knn: strided mapping,   idx = j*1024 + tid
#define NWAVE  16

typedef float v2f __attribute__((ext_vector_type(2)));

// DPP ctrl encodings (gfx9+): row_shr:N = 0x110|N, row_bcast15/31 = 0x142/0x143
template <int CTRL>
__device__ __forceinline__ float dpp_max_f32(float v) {
  // bound_ctrl=1 -> invalid source lanes read 0; all reduced values are
  // squared distances >= 0, so max-with-0 is identity-safe.
  const int t =
      __builtin_amdgcn_update_dpp(0, __float_as_int(v), CTRL, 0xf, 0xf, true);
  return fmaxf(v, __int_as_float(t));
}

// ws layout (uints): [0] ticket counter; [32 + b*32] progress[b]

// ---------------------------------------------------------------------------
// Fused kernel, ticket roles (deadlock-free under any dispatch order: fps
// tickets 0..15 go to the first-placed blocks, which never wait; knn tickets
// spin only on fps progress). 82 KB LDS pad -> 1 block/CU: fps CUs are never
// shared with knn waves (round-5 lesson), knn gets 16 waves/CU (4/SIMD).
//
// fps (validated bit-exact r2/r4/r7): d=(dx*dx+dy*dy)+dz*dz, contract off,
// fminf; argmax-first == value-max then min index == first lane (contiguous
// mapping) then min j (descending overwrite). NEW this round: winner coords
// ride in the reduce slots (register-select on the owner lane), level-2 is
// conflict-free (16 words/16 banks + same-address broadcasts). Selection
// arithmetic unchanged.
// knn (validated bit-exact r2): xx left-to-right, dot = fmaf chain (einsum),
// d2=(cc-2*dot)+xx, sortable-u32 map, u64 keys, ascending-index tie-break.
// Cross-XCD: fps publishes progress with agent-scope RELEASE; knn spins with
// agent-scope ACQUIRE and reads centers with agent-scope atomic loads
// (r5-validated pattern).
// ---------------------------------------------------------------------------
__global__ __launch_bounds__(TPB, 1) void fused_kernel(
    const float* __restrict__ points, float* __restrict__ grouped,
    float* __restrict__ centers, unsigned* __restrict__ ws) {
#pragma clang fp contract(off)
  __shared__ union {
    struct {  // fps role: ping-pong {val,x,y,z} slots
      float sval[2][NWAVE], sx[2][NWAVE], sy[2][NWAVE], sz[2][NWAVE];
    } f;
    struct {  // knn role
      unsigned long long wred[2][NWAVE];
      int knn_sh[GSZ];
    } k;
    char pad[82000];  // force 1 block/CU (160 KiB LDS per CU)
  } u;
  __shared__ unsigned ticket_sh;

  const int tid  = threadIdx.x;
  const int lane = tid & 63;
  const int wave = tid >> 6;

  if (tid == 0) ticket_sh = atomicAdd(ws, 1u);
  __syncthreads();
  const unsigned ticket = ticket_sh;

  if (ticket < BATCH) {
    // ================= FPS role: one block per batch =================
    const int b = (int)ticket;
    const float* P = points + (size_t)b * NPTS * NCH;
    float* C = centers + (size_t)b * NGRP * 3;
    unsigned* prog = ws + 32 + b * 32;

    v2f px[4], py[4], pz[4], md[4];
    {
      float* fx = (float*)px; float* fy = (float*)py; float* fz = (float*)pz;
#pragma unroll
      for (int j = 0; j < FPPT; ++j) {
        const int i = tid * FPPT + j;  // contiguous mapping
        fx[j] = P[i * 6 + 0];
        fy[j] = P[i * 6 + 1];
        fz[j] = P[i * 6 + 2];
      }
#pragma unroll
      for (int j = 0; j < 4; ++j)
        md[j] = (v2f){__builtin_inff(), __builtin_inff()};
    }
    // current center = point 0 (uniform broadcast load)
    float lx = P[0], ly = P[1], lz = P[2];

    for (int k = 1; k < NGRP; ++k) {
      if (tid == 0) {  // store center k-1; publish progress every 8
        C[(k - 1) * 3 + 0] = lx;
        C[(k - 1) * 3 + 1] = ly;
        C[(k - 1) * 3 + 2] = lz;
        if ((k & 7) == 0)
          __hip_atomic_store(prog, (unsigned)k, __ATOMIC_RELEASE,
                             __HIP_MEMORY_SCOPE_AGENT);
      }

      // ---- inner: packed min-dist update + per-thread max ----
      const v2f vlx = {lx, lx}, vly = {ly, ly}, vlz = {lz, lz};
      v2f b2 = {-__builtin_inff(), -__builtin_inff()};
#pragma unroll
      for (int j = 0; j < 4; ++j) {
        const v2f dx = px[j] - vlx;
        const v2f dy = py[j] - vly;
        const v2f dz = pz[j] - vlz;
        const v2f d  = (dx * dx + dy * dy) + dz * dz;  // ref order, no fma
        md[j] = __builtin_elementwise_min(md[j], d);
        b2 = __builtin_elementwise_max(b2, md[j]);
      }
      const float bestv = fmaxf(b2.x, b2.y);

      // ---- level-1: wave max via DPP, owner = first matching lane ----
      float wv = bestv;
      wv = dpp_max_f32<0x111>(wv); wv = dpp_max_f32<0x112>(wv);
      wv = dpp_max_f32<0x114>(wv); wv = dpp_max_f32<0x118>(wv);
      wv = dpp_max_f32<0x142>(wv); wv = dpp_max_f32<0x143>(wv);
      const float wvmax =
          __int_as_float(__builtin_amdgcn_readlane(__float_as_int(wv), 63));
      const int owner = (int)__builtin_ctzll(__ballot(bestv == wvmax));

      const int p = k & 1;
      if (lane == owner) {
        // select winning coords from registers: descending overwrite ends at
        // the lowest matching index (y-half first, then x-half, j descending)
        float fx = 0.f, fy = 0.f, fz = 0.f;
#pragma unroll
        for (int j = 3; j >= 0; --j) {
          if (md[j].y == bestv) { fx = px[j].y; fy = py[j].y; fz = pz[j].y; }
          if (md[j].x == bestv) { fx = px[j].x; fy = py[j].x; fz = pz[j].x; }
        }
        u.f.sval[p][wave] = wvmax;
        u.f.sx[p][wave] = fx; u.f.sy[p][wave] = fy; u.f.sz[p][wave] = fz;
      }
      __syncthreads();  // the only barrier per step

      // ---- level-2: 16 slots (16 banks, row-replicated -> conflict-free) --
      const float sval0 = u.f.sval[p][lane & 15];
      float r = sval0;
      r = dpp_max_f32<0x111>(r); r = dpp_max_f32<0x112>(r);
      r = dpp_max_f32<0x114>(r); r = dpp_max_f32<0x118>(r);
      const float gmax =
          __int_as_float(__builtin_amdgcn_readlane(__float_as_int(r), 15));
      const int sstar =
          (int)__builtin_ctzll(__ballot(sval0 == gmax) & 0xFFFFull);  // min wave
      lx = u.f.sx[p][sstar];  // same-address broadcast reads (free)
      ly = u.f.sy[p][sstar];
      lz = u.f.sz[p][sstar];
    }
    if (tid == 0) {  // final center + full publish
      C[(NGRP - 1) * 3 + 0] = lx;
      C[(NGRP - 1) * 3 + 1] = ly;
      C[(NGRP - 1) * 3 + 2] = lz;
      __hip_atomic_store(prog, (unsigned)NGRP, __ATOMIC_RELEASE,
                         __HIP_MEMORY_SCOPE_AGENT);
    }
  } else {
    // ================= kNN role: one block per (group, batch) =============
    // g-major ticket order: resident blocks' required progress ascends in
    // lockstep with all 16 fps blocks -> short spins.
    const unsigned gid = ticket - BATCH;
    const int g = (int)(gid >> 4);
    const int b = (int)(gid & 15);
    const float* P = points + (size_t)b * NPTS * NCH;
    const float* cen = centers + ((size_t)b * NGRP + g) * 3;
    unsigned* prog = ws + 32 + b * 32;

    if (tid == 0) {  // spin until center g is published
      while (__hip_atomic_load(prog, __ATOMIC_ACQUIRE,
                               __HIP_MEMORY_SCOPE_AGENT) < (unsigned)(g + 1))
        __builtin_amdgcn_s_sleep(16);
    }
    __syncthreads();

    // center via agent-scope atomic loads (fresh across XCDs; r5-validated)
    const float cx = __hip_atomic_load(&cen[0], __ATOMIC_RELAXED,
                                       __HIP_MEMORY_SCOPE_AGENT);
    const float cy = __hip_atomic_load(&cen[1], __ATOMIC_RELAXED,
                                       __HIP_MEMORY_SCOPE_AGENT);
    const float cz = __hip_atomic_load(&cen[2], __ATOMIC_RELAXED,
                                       __HIP_MEMORY_SCOPE_AGENT);
    const float cc = (cx * cx + cy * cy) + cz * cz;

    unsigned long long keys[KPPT];
#pragma unroll
    for (int j = 0; j < KPPT; ++j) {
      const int i = j * TPB + tid;  // strided mapping (coalesced loads)
      const float x = P[i * 6 + 0];
      const float y = P[i * 6 + 1];
      const float z = P[i * 6 + 2];
      const float xx  = (x * x + y * y) + z * z;
      const float dot = fmaf(cz, z, fmaf(cy, y, cx * x));  // einsum fma chain
      const float d2  = (cc - 2.0f * dot) + xx;
      unsigned v = __float_as_uint(d2);
      v = (v & 0x80000000u) ? ~v : (v | 0x80000000u);  // sortable map
      keys[j] = ((unsigned long long)v << 32) | (unsigned long long)(unsigned)i;
    }
    unsigned long long lmin = keys[0];
#pragma unroll
    for (int j = 1; j < KPPT; ++j) lmin = lmin < keys[j] ? lmin : keys[j];

    for (int j = 0; j < GSZ; ++j) {
      unsigned long long v = lmin;
#pragma unroll
      for (int off = 32; off >= 1; off >>= 1) {
        const unsigned long long o = __shfl_xor(v, off);
        v = v < o ? v : o;
      }
      if (lane == 0) u.k.wred[j & 1][wave] = v;
      __syncthreads();
      unsigned long long w = u.k.wred[j & 1][lane & 15];
#pragma unroll
      for (int off = 8; off >= 1; off >>= 1) {
        const unsigned long long o = __shfl_xor(w, off);
        w = w < o ? w : o;
      }
      const int widx = (int)(unsigned)(w & 0xFFFFFFFFull);
      if (tid == (widx & (TPB - 1))) {  // owner removes winner, rebuilds min
#pragma unroll
        for (int s = 0; s < KPPT; ++s)
          if ((unsigned)(keys[s] & 0xFFFFFFFFull) == (unsigned)widx)
            keys[s] = ~0ull;
        lmin = keys[0];
#pragma unroll
        for (int s = 1; s < KPPT; ++s) lmin = lmin < keys[s] ? lmin : keys[s];
      }
      if (tid == 0) u.k.knn_sh[j] = widx;
    }
    __syncthreads();

    // gather + center-relative xyz; 192 output floats per group
    float* outg = grouped + ((size_t)b * NGRP + g) * GSZ * NCH;
    if (tid < GSZ * NCH) {
      const int n = tid / 6, c = tid % 6;
      const int idx = u.k.knn_sh[n];
      float v2 = P[idx * 6 + c];
      if (c < 3) {
        const float cv = (c == 0) ? cx : (c == 1) ? cy : cz;
        v2 = v2 - cv;  // exact ref subtract
      }
      outg[tid] = v2;
    }
  }
}

extern "C" void kernel_launch(void* const* d_in, const int* in_sizes, int n_in,
                              void* d_out, int out_size, void* d_ws, size_t ws_size,
                              hipStream_t stream) {
  const float* points = (const float*)d_in[0];
  float* out = (float*)d_out;
  float* grouped = out;                                        // [16,512,32,6]
  float* centers = out + (size_t)BATCH * NGRP * GSZ * NCH;     // [16,512,3]
  unsigned* ws = (unsigned*)d_ws;

  // zero ticket counter + progress flags (ws is poisoned 0xAA pre-launch)
  hipMemsetAsync(ws, 0, 4096, stream);
  fused_kernel<<<BATCH + BATCH * NGRP, TPB, 0, stream>>>(points, grouped,
                                                         centers, ws);
}

// Round 9
// 900.119 us; speedup vs baseline: 1.7723x; 1.7723x over previous
//
#include <hip/hip_runtime.h>
#include <hip/hip_bf16.h>
#include <stdint.h>

// Problem constants (fixed by reference)
#define BATCH 16
#define NPTS  8192
#define NCH   6
#define NGRP  512   // NUM_GROUPS (FPS samples)
#define GSZ   32    // GROUP_SIZE (kNN)

#define FPS_T   1024              // 16 waves, 4/SIMD
#define FPPT    8                 // contiguous: idx = tid*8 + j
#define FPS_W   16

typedef float v2f __attribute__((ext_vector_type(2)));

// DPP ctrl encodings (gfx9+): row_shr:N = 0x110|N, row_bcast15/31 = 0x142/0x143
template <int CTRL>
__device__ __forceinline__ float dpp_max_f32(float v) {
  // bound_ctrl=1 -> invalid source lanes read 0; all reduced values are
  // squared distances >= 0, so max-with-0 is identity-safe.
  const int t =
      __builtin_amdgcn_update_dpp(0, __float_as_int(v), CTRL, 0xf, 0xf, true);
  return fmaxf(v, __int_as_float(t));
}

// ---------------------------------------------------------------------------
// Kernel 1: farthest point sampling. One block per batch (16 CUs active).
// Round-9 = round-7 DPP/ballot structure + round-8's coord transport
// (validated bit-exact by r8's absmax 0.0): the level-1 owner lane selects
// its winning point's xyz from REGISTERS (descending overwrite = lowest
// index) and writes {val,x,y,z} to per-wave slots; level-2 is a conflict-free
// 16-slot DPP max + ballot (min wave) + same-address broadcast coord reads.
// No 96 KiB cache, no conflicted gathers, no readlane chains.
//
// Numerics (bit-exact, r2/r4/r7/r8): d = (dx*dx+dy*dy)+dz*dz, contract off
// (pk ops per-element IEEE), fminf running min; argmax-first == value max,
// then min index == first lane (contiguous mapping), then min j
// (descending overwrite); cross-wave ties -> min wave via ballot ctz.
// ---------------------------------------------------------------------------
__global__ __launch_bounds__(FPS_T, 1) void fps_kernel(
    const float* __restrict__ points, float* __restrict__ centers) {
#pragma clang fp contract(off)
  const int b    = blockIdx.x;
  const int tid  = threadIdx.x;
  const int lane = tid & 63;
  const int wave = tid >> 6;
  const float* P = points + (size_t)b * NPTS * NCH;
  float* C = centers + (size_t)b * NGRP * 3;

  __shared__ float sval[2][FPS_W], sx[2][FPS_W], sy[2][FPS_W], sz[2][FPS_W];

  v2f px[4], py[4], pz[4], md[4];
  {
    float* fx = (float*)px; float* fy = (float*)py; float* fz = (float*)pz;
#pragma unroll
    for (int j = 0; j < FPPT; ++j) {
      const int i = tid * FPPT + j;  // contiguous mapping
      fx[j] = P[i * 6 + 0];
      fy[j] = P[i * 6 + 1];
      fz[j] = P[i * 6 + 2];
    }
#pragma unroll
    for (int j = 0; j < 4; ++j)
      md[j] = (v2f){__builtin_inff(), __builtin_inff()};
  }
  // current center = point 0 (uniform broadcast load)
  float lx = P[0], ly = P[1], lz = P[2];

  for (int k = 1; k < NGRP; ++k) {
    if (tid == 0) {  // store center k-1 (uniform regs, off critical path)
      C[(k - 1) * 3 + 0] = lx;
      C[(k - 1) * 3 + 1] = ly;
      C[(k - 1) * 3 + 2] = lz;
    }

    // ---- inner: packed min-dist update + per-thread max ----
    const v2f vlx = {lx, lx}, vly = {ly, ly}, vlz = {lz, lz};
    v2f b2 = {-__builtin_inff(), -__builtin_inff()};
#pragma unroll
    for (int j = 0; j < 4; ++j) {
      const v2f dx = px[j] - vlx;
      const v2f dy = py[j] - vly;
      const v2f dz = pz[j] - vlz;
      const v2f d  = (dx * dx + dy * dy) + dz * dz;  // ref order, no fma
      md[j] = __builtin_elementwise_min(md[j], d);
      b2 = __builtin_elementwise_max(b2, md[j]);
    }
    const float bestv = fmaxf(b2.x, b2.y);

    // ---- level-1: wave max via DPP, owner = first matching lane ----
    float wv = bestv;
    wv = dpp_max_f32<0x111>(wv); wv = dpp_max_f32<0x112>(wv);
    wv = dpp_max_f32<0x114>(wv); wv = dpp_max_f32<0x118>(wv);
    wv = dpp_max_f32<0x142>(wv); wv = dpp_max_f32<0x143>(wv);
    const float wvmax =
        __int_as_float(__builtin_amdgcn_readlane(__float_as_int(wv), 63));
    const int owner = (int)__builtin_ctzll(__ballot(bestv == wvmax));

    const int p = k & 1;
    if (lane == owner) {
      // coords of the LOWEST matching index: descending overwrite
      // (y-half = odd idx before x-half = even idx, j descending)
      float fx = 0.f, fy = 0.f, fz = 0.f;
#pragma unroll
      for (int j = 3; j >= 0; --j) {
        if (md[j].y == bestv) { fx = px[j].y; fy = py[j].y; fz = pz[j].y; }
        if (md[j].x == bestv) { fx = px[j].x; fy = py[j].x; fz = pz[j].x; }
      }
      sval[p][wave] = wvmax;
      sx[p][wave] = fx; sy[p][wave] = fy; sz[p][wave] = fz;
    }
    __syncthreads();  // the only barrier per step

    // ---- level-2: 16 slots (16 banks, 4-to-1 same-addr -> broadcast) ----
    const float sval0 = sval[p][lane & 15];
    float r = sval0;
    r = dpp_max_f32<0x111>(r); r = dpp_max_f32<0x112>(r);
    r = dpp_max_f32<0x114>(r); r = dpp_max_f32<0x118>(r);
    const float gmax =
        __int_as_float(__builtin_amdgcn_readlane(__float_as_int(r), 15));
    const int sstar =
        (int)__builtin_ctzll(__ballot(sval0 == gmax) & 0xFFFFull);  // min wave
    lx = sx[p][sstar];  // same-address broadcast reads
    ly = sy[p][sstar];
    lz = sz[p][sstar];
  }
  if (tid == 0) {  // final center
    C[(NGRP - 1) * 3 + 0] = lx;
    C[(NGRP - 1) * 3 + 1] = ly;
    C[(NGRP - 1) * 3 + 2] = lz;
  }
}

// ---------------------------------------------------------------------------
// Kernel 2: 32-NN per (batch, group) + gather + center-relative output.
// (round-2 version, validated bit-exact; best measured config: 256 threads,
// multi-block occupancy overlaps the per-round reduce latency)
// ---------------------------------------------------------------------------
__global__ __launch_bounds__(256) void knn_kernel(
    const float* __restrict__ points, const float* __restrict__ centers,
    float* __restrict__ grouped) {
#pragma clang fp contract(off)
  const int g    = blockIdx.x;
  const int b    = blockIdx.y;
  const int tid  = threadIdx.x;
  const int lane = tid & 63;
  const int wave = tid >> 6;
  const float* P   = points + (size_t)b * NPTS * NCH;
  const float* cen = centers + ((size_t)b * NGRP + g) * 3;
  const float cx = cen[0], cy = cen[1], cz = cen[2];
  const float cc = (cx * cx + cy * cy) + cz * cz;

  unsigned long long keys[32];
  for (int j = 0; j < 32; ++j) {
    const int i = j * 256 + tid;
    const float x = P[i * 6 + 0];
    const float y = P[i * 6 + 1];
    const float z = P[i * 6 + 2];
    const float xx  = (x * x + y * y) + z * z;
    const float dot = fmaf(cz, z, fmaf(cy, y, cx * x));  // einsum fma chain
    const float d2  = (cc - 2.0f * dot) + xx;
    unsigned u = __float_as_uint(d2);
    u = (u & 0x80000000u) ? ~u : (u | 0x80000000u);  // sortable map
    keys[j] = ((unsigned long long)u << 32) | (unsigned long long)(unsigned)i;
  }
  unsigned long long lmin = keys[0];
  for (int j = 1; j < 32; ++j) lmin = lmin < keys[j] ? lmin : keys[j];

  __shared__ unsigned long long wred[2][4];
  __shared__ int knn_sh[GSZ];

  for (int j = 0; j < GSZ; ++j) {
    unsigned long long v = lmin;
    for (int off = 32; off >= 1; off >>= 1) {
      const unsigned long long o = __shfl_down(v, off);
      v = v < o ? v : o;
    }
    if (lane == 0) wred[j & 1][wave] = v;
    __syncthreads();
    unsigned long long w = wred[j & 1][0];
    for (int q2 = 1; q2 < 4; ++q2) {
      const unsigned long long o = wred[j & 1][q2];
      w = w < o ? w : o;
    }
    const int widx = (int)(unsigned)(w & 0xFFFFFFFFull);
    if (tid == (widx & 255)) {  // owner removes winner, rebuilds local min
      for (int s = 0; s < 32; ++s)
        if ((unsigned)(keys[s] & 0xFFFFFFFFull) == (unsigned)widx)
          keys[s] = ~0ull;
      lmin = keys[0];
      for (int s = 1; s < 32; ++s) lmin = lmin < keys[s] ? lmin : keys[s];
    }
    if (tid == 0) knn_sh[j] = widx;
  }
  __syncthreads();

  // gather + center-relative xyz; 192 output floats per group
  float* outg = grouped + ((size_t)b * NGRP + g) * GSZ * NCH;
  for (int t = tid; t < GSZ * NCH; t += 256) {
    const int n = t / 6, c = t % 6;
    const int idx = knn_sh[n];
    float v = P[idx * 6 + c];
    if (c < 3) v = v - cen[c];  // exact ref subtract
    outg[t] = v;
  }
}

extern "C" void kernel_launch(void* const* d_in, const int* in_sizes, int n_in,
                              void* d_out, int out_size, void* d_ws, size_t ws_size,
                              hipStream_t stream) {
  const float* points = (const float*)d_in[0];
  float* out = (float*)d_out;
  float* grouped = out;                                        // [16,512,32,6]
  float* centers = out + (size_t)BATCH * NGRP * GSZ * NCH;     // [16,512,3]

  fps_kernel<<<BATCH, FPS_T, 0, stream>>>(points, centers);
  knn_kernel<<<dim3(NGRP, BATCH), 256, 0, stream>>>(points, centers, grouped);
}

// Round 10
// 891.623 us; speedup vs baseline: 1.7892x; 1.0095x over previous
//
#include <hip/hip_runtime.h>
#include <hip/hip_bf16.h>
#include <stdint.h>

// Problem constants (fixed by reference)
#define BATCH 16
#define NPTS  8192
#define NCH   6
#define NGRP  512   // NUM_GROUPS (FPS samples)
#define GSZ   32    // GROUP_SIZE (kNN)

#define FPS_T   1024              // 16 waves, 4/SIMD
#define FPPT    8                 // contiguous: idx = tid*8 + j
#define FPS_W   16

typedef float v2f __attribute__((ext_vector_type(2)));

// DPP ctrl encodings (gfx9+): row_shr:N = 0x110|N, row_bcast15/31 = 0x142/0x143
template <int CTRL>
__device__ __forceinline__ float dpp_max_f32(float v) {
  // bound_ctrl=1 -> invalid source lanes read 0; reduced values are squared
  // distances >= 0, so max-with-0 is identity-safe. (validated r7/r8/r9)
  const int t =
      __builtin_amdgcn_update_dpp(0, __float_as_int(v), CTRL, 0xf, 0xf, true);
  return fmaxf(v, __int_as_float(t));
}

template <int CTRL>
__device__ __forceinline__ unsigned dpp_min_u32(unsigned v) {
  // bound_ctrl=0 + old=0xFFFFFFFF -> invalid source lanes yield the min
  // identity, so the chain computes an exact u32 min.
  const int t = __builtin_amdgcn_update_dpp((int)0xFFFFFFFF, (int)v, CTRL,
                                            0xf, 0xf, false);
  const unsigned tu = (unsigned)t;
  return v < tu ? v : tu;
}

// ---------------------------------------------------------------------------
// Kernel 1: farthest point sampling. One block per batch (16 CUs active).
// Round-10 = r9's conflict-free slot transport + r7's speculative-read +
// readlane finish (shortest post-barrier chain of any round):
//   owner lane writes {val,x} and {y,z} float2 slots (16 slots x 8 B = all
//   32 banks; 4-way same-address replication = broadcast, conflict-free);
//   after the barrier each lane speculatively reads slot lane&15 (overlaps
//   the DPP value reduce), ballot picks the min matching wave, coords come
//   via 3 readlanes (VALU) -- no dependent LDS read after the ballot.
//
// Numerics (bit-exact, r2/r4/r7/r8/r9): d = (dx*dx+dy*dy)+dz*dz, contract
// off, fminf running min; argmax-first == value max, then min index ==
// first lane (contiguous mapping), then min j (descending overwrite);
// cross-wave ties -> min wave via ballot ctz.
// ---------------------------------------------------------------------------
__global__ __launch_bounds__(FPS_T, 1) void fps_kernel(
    const float* __restrict__ points, float* __restrict__ centers) {
#pragma clang fp contract(off)
  const int b    = blockIdx.x;
  const int tid  = threadIdx.x;
  const int lane = tid & 63;
  const int wave = tid >> 6;
  const float* P = points + (size_t)b * NPTS * NCH;
  float* C = centers + (size_t)b * NGRP * 3;

  __shared__ v2f sVX[2][FPS_W];  // {val, x}
  __shared__ v2f sYZ[2][FPS_W];  // {y, z}

  v2f px[4], py[4], pz[4], md[4];
  {
    float* fx = (float*)px; float* fy = (float*)py; float* fz = (float*)pz;
#pragma unroll
    for (int j = 0; j < FPPT; ++j) {
      const int i = tid * FPPT + j;  // contiguous mapping
      fx[j] = P[i * 6 + 0];
      fy[j] = P[i * 6 + 1];
      fz[j] = P[i * 6 + 2];
    }
#pragma unroll
    for (int j = 0; j < 4; ++j)
      md[j] = (v2f){__builtin_inff(), __builtin_inff()};
  }
  // current center = point 0 (uniform broadcast load)
  float lx = P[0], ly = P[1], lz = P[2];

  for (int k = 1; k < NGRP; ++k) {
    if (tid == 0) {  // store center k-1 (uniform regs, off critical path)
      C[(k - 1) * 3 + 0] = lx;
      C[(k - 1) * 3 + 1] = ly;
      C[(k - 1) * 3 + 2] = lz;
    }

    // ---- inner: packed min-dist update + per-thread max ----
    const v2f vlx = {lx, lx}, vly = {ly, ly}, vlz = {lz, lz};
    v2f b2 = {-__builtin_inff(), -__builtin_inff()};
#pragma unroll
    for (int j = 0; j < 4; ++j) {
      const v2f dx = px[j] - vlx;
      const v2f dy = py[j] - vly;
      const v2f dz = pz[j] - vlz;
      const v2f d  = (dx * dx + dy * dy) + dz * dz;  // ref order, no fma
      md[j] = __builtin_elementwise_min(md[j], d);
      b2 = __builtin_elementwise_max(b2, md[j]);
    }
    const float bestv = fmaxf(b2.x, b2.y);

    // ---- level-1: wave max via DPP, owner = first matching lane ----
    float wv = bestv;
    wv = dpp_max_f32<0x111>(wv); wv = dpp_max_f32<0x112>(wv);
    wv = dpp_max_f32<0x114>(wv); wv = dpp_max_f32<0x118>(wv);
    wv = dpp_max_f32<0x142>(wv); wv = dpp_max_f32<0x143>(wv);
    const float wvmax =
        __int_as_float(__builtin_amdgcn_readlane(__float_as_int(wv), 63));
    const int owner = (int)__builtin_ctzll(__ballot(bestv == wvmax));

    const int p = k & 1;
    if (lane == owner) {
      // coords of the LOWEST matching index: descending overwrite
      // (y-half = odd idx before x-half = even idx, j descending)
      float fx = 0.f, fy = 0.f, fz = 0.f;
#pragma unroll
      for (int j = 3; j >= 0; --j) {
        if (md[j].y == bestv) { fx = px[j].y; fy = py[j].y; fz = pz[j].y; }
        if (md[j].x == bestv) { fx = px[j].x; fy = py[j].x; fz = pz[j].x; }
      }
      sVX[p][wave] = (v2f){wvmax, fx};
      sYZ[p][wave] = (v2f){fy, fz};
    }
    __syncthreads();  // the only barrier per step

    // ---- level-2: speculative slot read overlaps the DPP reduce ----
    const v2f vx = sVX[p][lane & 15];  // conflict-free broadcast pattern
    const v2f yz = sYZ[p][lane & 15];
    float r = vx.x;
    r = dpp_max_f32<0x111>(r); r = dpp_max_f32<0x112>(r);
    r = dpp_max_f32<0x114>(r); r = dpp_max_f32<0x118>(r);
    const float gmax =
        __int_as_float(__builtin_amdgcn_readlane(__float_as_int(r), 15));
    const int sstar =
        (int)__builtin_ctzll(__ballot(vx.x == gmax) & 0xFFFFull);  // min wave
    lx = __int_as_float(__builtin_amdgcn_readlane(__float_as_int(vx.y), sstar));
    ly = __int_as_float(__builtin_amdgcn_readlane(__float_as_int(yz.x), sstar));
    lz = __int_as_float(__builtin_amdgcn_readlane(__float_as_int(yz.y), sstar));
  }
  if (tid == 0) {  // final center
    C[(NGRP - 1) * 3 + 0] = lx;
    C[(NGRP - 1) * 3 + 1] = ly;
    C[(NGRP - 1) * 3 + 2] = lz;
  }
}

// ---------------------------------------------------------------------------
// Kernel 2: 32-NN per (batch, group) + gather + center-relative output.
// Round-10: the per-round wave reduce switches from 6-stage u64 __shfl_xor
// (DS pipe, contended across ~6 co-resident blocks/CU) to a VALU-only DPP
// pair: u32 min of sortable val -> readlane -> u32 min of (match?idx:~0).
// This is exactly the lexicographic (val,idx) u64-key min of r2, so
// selection and tie-breaks are unchanged. Level-2 + owner removal verbatim.
// ---------------------------------------------------------------------------
__global__ __launch_bounds__(256) void knn_kernel(
    const float* __restrict__ points, const float* __restrict__ centers,
    float* __restrict__ grouped) {
#pragma clang fp contract(off)
  const int g    = blockIdx.x;
  const int b    = blockIdx.y;
  const int tid  = threadIdx.x;
  const int lane = tid & 63;
  const int wave = tid >> 6;
  const float* P   = points + (size_t)b * NPTS * NCH;
  const float* cen = centers + ((size_t)b * NGRP + g) * 3;
  const float cx = cen[0], cy = cen[1], cz = cen[2];
  const float cc = (cx * cx + cy * cy) + cz * cz;

  unsigned long long keys[32];
  for (int j = 0; j < 32; ++j) {
    const int i = j * 256 + tid;
    const float x = P[i * 6 + 0];
    const float y = P[i * 6 + 1];
    const float z = P[i * 6 + 2];
    const float xx  = (x * x + y * y) + z * z;
    const float dot = fmaf(cz, z, fmaf(cy, y, cx * x));  // einsum fma chain
    const float d2  = (cc - 2.0f * dot) + xx;
    unsigned u = __float_as_uint(d2);
    u = (u & 0x80000000u) ? ~u : (u | 0x80000000u);  // sortable map
    keys[j] = ((unsigned long long)u << 32) | (unsigned long long)(unsigned)i;
  }
  unsigned long long lmin = keys[0];
  for (int j = 1; j < 32; ++j) lmin = lmin < keys[j] ? lmin : keys[j];

  __shared__ unsigned long long wred[2][4];
  __shared__ int knn_sh[GSZ];

  for (int j = 0; j < GSZ; ++j) {
    // ---- wave reduce: VALU-only DPP pair == u64 (val,idx) lexicographic min
    const unsigned vcur = (unsigned)(lmin >> 32);
    const unsigned icur = (unsigned)(lmin & 0xFFFFFFFFull);
    unsigned vm = vcur;
    vm = dpp_min_u32<0x111>(vm); vm = dpp_min_u32<0x112>(vm);
    vm = dpp_min_u32<0x114>(vm); vm = dpp_min_u32<0x118>(vm);
    vm = dpp_min_u32<0x142>(vm); vm = dpp_min_u32<0x143>(vm);
    const unsigned vmin =
        (unsigned)__builtin_amdgcn_readlane((int)vm, 63);
    unsigned ic = (vcur == vmin) ? icur : 0xFFFFFFFFu;
    ic = dpp_min_u32<0x111>(ic); ic = dpp_min_u32<0x112>(ic);
    ic = dpp_min_u32<0x114>(ic); ic = dpp_min_u32<0x118>(ic);
    ic = dpp_min_u32<0x142>(ic); ic = dpp_min_u32<0x143>(ic);
    const unsigned imin =
        (unsigned)__builtin_amdgcn_readlane((int)ic, 63);

    if (lane == 0)
      wred[j & 1][wave] =
          ((unsigned long long)vmin << 32) | (unsigned long long)imin;
    __syncthreads();
    unsigned long long w = wred[j & 1][0];
    for (int q2 = 1; q2 < 4; ++q2) {
      const unsigned long long o = wred[j & 1][q2];
      w = w < o ? w : o;
    }
    const int widx = (int)(unsigned)(w & 0xFFFFFFFFull);
    if (tid == (widx & 255)) {  // owner removes winner, rebuilds local min
      for (int s = 0; s < 32; ++s)
        if ((unsigned)(keys[s] & 0xFFFFFFFFull) == (unsigned)widx)
          keys[s] = ~0ull;
      lmin = keys[0];
      for (int s = 1; s < 32; ++s) lmin = lmin < keys[s] ? lmin : keys[s];
    }
    if (tid == 0) knn_sh[j] = widx;
  }
  __syncthreads();

  // gather + center-relative xyz; 192 output floats per group
  float* outg = grouped + ((size_t)b * NGRP + g) * GSZ * NCH;
  for (int t = tid; t < GSZ * NCH; t += 256) {
    const int n = t / 6, c = t % 6;
    const int idx = knn_sh[n];
    float v = P[idx * 6 + c];
    if (c < 3) v = v - cen[c];  // exact ref subtract
    outg[t] = v;
  }
}

extern "C" void kernel_launch(void* const* d_in, const int* in_sizes, int n_in,
                              void* d_out, int out_size, void* d_ws, size_t ws_size,
                              hipStream_t stream) {
  const float* points = (const float*)d_in[0];
  float* out = (float*)d_out;
  float* grouped = out;                                        // [16,512,32,6]
  float* centers = out + (size_t)BATCH * NGRP * GSZ * NCH;     // [16,512,3]

  fps_kernel<<<BATCH, FPS_T, 0, stream>>>(points, centers);
  knn_kernel<<<dim3(NGRP, BATCH), 256, 0, stream>>>(points, centers, grouped);
}

// Round 11
// 805.657 us; speedup vs baseline: 1.9801x; 1.1067x over previous
//
#include <hip/hip_runtime.h>
#include <hip/hip_bf16.h>
#include <stdint.h>

// Problem constants (fixed by reference)
#define BATCH 16
#define NPTS  8192
#define NCH   6
#define NGRP  512   // NUM_GROUPS (FPS samples)
#define GSZ   32    // GROUP_SIZE (kNN)

#define FPS_T   1024              // 16 waves, 4/SIMD
#define FPS_PPT 8                 // contiguous: idx = tid*8 + j
#define FPS_W   16

typedef float v2f __attribute__((ext_vector_type(2)));

// DPP ctrl encodings (gfx9+): row_shr:N = 0x110|N, row_bcast15/31 = 0x142/0x143
template <int CTRL>
__device__ __forceinline__ float dpp_max_f32(float v) {
  // bound_ctrl=1 -> invalid source lanes read 0; reduced values are squared
  // distances >= 0, so max-with-0 is identity-safe. (validated r7-r10)
  const int t =
      __builtin_amdgcn_update_dpp(0, __float_as_int(v), CTRL, 0xf, 0xf, true);
  return fmaxf(v, __int_as_float(t));
}

template <int CTRL>
__device__ __forceinline__ unsigned dpp_min_u32(unsigned v) {
  // bound_ctrl=0 + old=0xFFFFFFFF -> invalid source lanes yield the min
  // identity, so the chain computes an exact u32 min. (validated r10)
  const int t = __builtin_amdgcn_update_dpp((int)0xFFFFFFFF, (int)v, CTRL,
                                            0xf, 0xf, false);
  const unsigned tu = (unsigned)t;
  return v < tu ? v : tu;
}

// ---------------------------------------------------------------------------
// Kernel 1: farthest point sampling — ROUND-7 VERBATIM (best measured:
// 517-533 us). One block per batch. One barrier/step, DPP level-1 reduce,
// ballot index resolution under contiguous mapping (idx = tid*8+j), owner
// writes a single u64 key, level-2 reads 16 slots + SPECULATIVE coord
// gathers from a 96 KiB LDS cache overlapping the level-2 DPP chain,
// readlane finish. (r9/r10 variants of this structure measured slower.)
//
// Numerics (bit-exact, r2/r4/r7): d = (dx*dx+dy*dy)+dz*dz, contract off
// (pk ops per-element IEEE), fminf running min. argmax-first == value max,
// then min index == first matching lane (contiguous mapping), then min j
// (descending overwrite). Cross-wave ties -> min wave via ballot ctz.
// ---------------------------------------------------------------------------
__global__ __launch_bounds__(FPS_T, 1) void fps_kernel(
    const float* __restrict__ points, float* __restrict__ centers) {
#pragma clang fp contract(off)
  const int b    = blockIdx.x;
  const int tid  = threadIdx.x;
  const int lane = tid & 63;
  const int wave = tid >> 6;
  const float* P = points + (size_t)b * NPTS * NCH;
  float* C = centers + (size_t)b * NGRP * 3;

  __shared__ float cache[NPTS * 3];                    // xyz cache, 96 KiB
  __shared__ unsigned long long wslot[2][FPS_W];       // ping-pong slots

  v2f px[4], py[4], pz[4], md[4];
  {
    float* fx = (float*)px; float* fy = (float*)py; float* fz = (float*)pz;
#pragma unroll
    for (int j = 0; j < FPS_PPT; ++j) {
      const int i = tid * FPS_PPT + j;   // contiguous mapping
      const float x = P[i * 6 + 0];
      const float y = P[i * 6 + 1];
      const float z = P[i * 6 + 2];
      fx[j] = x; fy[j] = y; fz[j] = z;
      cache[i * 3 + 0] = x;
      cache[i * 3 + 1] = y;
      cache[i * 3 + 2] = z;
    }
#pragma unroll
    for (int j = 0; j < 4; ++j) md[j] = (v2f){__builtin_inff(), __builtin_inff()};
  }
  __syncthreads();  // cache ready

  // current center = point 0
  float lx = cache[0], ly = cache[1], lz = cache[2];

  for (int k = 1; k < NGRP; ++k) {
    if (tid == 0) {  // store center k-1 (uniform regs, off critical path)
      C[(k - 1) * 3 + 0] = lx; C[(k - 1) * 3 + 1] = ly; C[(k - 1) * 3 + 2] = lz;
    }

    // ---- inner: packed min-dist update + per-thread max ----
    const v2f vlx = {lx, lx}, vly = {ly, ly}, vlz = {lz, lz};
    v2f b2 = {-__builtin_inff(), -__builtin_inff()};
#pragma unroll
    for (int j = 0; j < 4; ++j) {
      const v2f dx = px[j] - vlx;
      const v2f dy = py[j] - vly;
      const v2f dz = pz[j] - vlz;
      const v2f d  = (dx * dx + dy * dy) + dz * dz;  // ref op order, no fma
      md[j] = __builtin_elementwise_min(md[j], d);
      b2 = __builtin_elementwise_max(b2, md[j]);
    }
    const float bestv = fmaxf(b2.x, b2.y);

    // first (min) index attaining bestv: descending scan ends at min j
    unsigned idxbest = 0;
#pragma unroll
    for (int j = 3; j >= 0; --j) {
      idxbest = (md[j].y == bestv) ? (unsigned)(tid * 8 + 2 * j + 1) : idxbest;
      idxbest = (md[j].x == bestv) ? (unsigned)(tid * 8 + 2 * j)     : idxbest;
    }

    // ---- level-1: wave max via DPP (VALU only) ----
    float wv = bestv;
    wv = dpp_max_f32<0x111>(wv); wv = dpp_max_f32<0x112>(wv);
    wv = dpp_max_f32<0x114>(wv); wv = dpp_max_f32<0x118>(wv);
    wv = dpp_max_f32<0x142>(wv); wv = dpp_max_f32<0x143>(wv);
    const float wvmax =
        __int_as_float(__builtin_amdgcn_readlane(__float_as_int(wv), 63));

    // owner = first lane attaining wave max (== min index owner)
    const unsigned long long m1 = __ballot(bestv == wvmax);
    const int owner = (int)__builtin_ctzll(m1);
    if (lane == owner)
      wslot[k & 1][wave] =
          ((unsigned long long)__float_as_uint(wvmax) << 32) | idxbest;
    __syncthreads();  // the only barrier per step

    // ---- level-2: 16 slots, row-replicated; DPP row max + ballot ----
    const unsigned long long slot = wslot[k & 1][lane & 15];
    const unsigned sidx = (unsigned)(slot & 0xFFFFFFFFull);
    const float    sval = __uint_as_float((unsigned)(slot >> 32));
    // speculative candidate coords (overlaps the DPP reduce below)
    const float ccx = cache[sidx * 3 + 0];
    const float ccy = cache[sidx * 3 + 1];
    const float ccz = cache[sidx * 3 + 2];

    float r = sval;
    r = dpp_max_f32<0x111>(r); r = dpp_max_f32<0x112>(r);
    r = dpp_max_f32<0x114>(r); r = dpp_max_f32<0x118>(r);
    const float gmax =
        __int_as_float(__builtin_amdgcn_readlane(__float_as_int(r), 15));
    const int sstar =
        (int)__builtin_ctzll(__ballot(sval == gmax) & 0xFFFFull);  // min wave
    lx = __int_as_float(__builtin_amdgcn_readlane(__float_as_int(ccx), sstar));
    ly = __int_as_float(__builtin_amdgcn_readlane(__float_as_int(ccy), sstar));
    lz = __int_as_float(__builtin_amdgcn_readlane(__float_as_int(ccz), sstar));
  }
  if (tid == 0) {  // final center
    C[(NGRP - 1) * 3 + 0] = lx;
    C[(NGRP - 1) * 3 + 1] = ly;
    C[(NGRP - 1) * 3 + 2] = lz;
  }
}

// ---------------------------------------------------------------------------
// Kernel 2: 32-NN per (batch, group) — ROUND-10 VERBATIM (best measured:
// ~268 us). VALU-only DPP pair per round (u32 val-min then idx-min ==
// lexicographic u64 key min, identical tie-breaks), level-2 + owner removal
// from r2.
// ---------------------------------------------------------------------------
__global__ __launch_bounds__(256) void knn_kernel(
    const float* __restrict__ points, const float* __restrict__ centers,
    float* __restrict__ grouped) {
#pragma clang fp contract(off)
  const int g    = blockIdx.x;
  const int b    = blockIdx.y;
  const int tid  = threadIdx.x;
  const int lane = tid & 63;
  const int wave = tid >> 6;
  const float* P   = points + (size_t)b * NPTS * NCH;
  const float* cen = centers + ((size_t)b * NGRP + g) * 3;
  const float cx = cen[0], cy = cen[1], cz = cen[2];
  const float cc = (cx * cx + cy * cy) + cz * cz;

  unsigned long long keys[32];
  for (int j = 0; j < 32; ++j) {
    const int i = j * 256 + tid;
    const float x = P[i * 6 + 0];
    const float y = P[i * 6 + 1];
    const float z = P[i * 6 + 2];
    const float xx  = (x * x + y * y) + z * z;
    const float dot = fmaf(cz, z, fmaf(cy, y, cx * x));  // einsum fma chain
    const float d2  = (cc - 2.0f * dot) + xx;
    unsigned u = __float_as_uint(d2);
    u = (u & 0x80000000u) ? ~u : (u | 0x80000000u);  // sortable map
    keys[j] = ((unsigned long long)u << 32) | (unsigned long long)(unsigned)i;
  }
  unsigned long long lmin = keys[0];
  for (int j = 1; j < 32; ++j) lmin = lmin < keys[j] ? lmin : keys[j];

  __shared__ unsigned long long wred[2][4];
  __shared__ int knn_sh[GSZ];

  for (int j = 0; j < GSZ; ++j) {
    // ---- wave reduce: VALU-only DPP pair == u64 (val,idx) lexicographic min
    const unsigned vcur = (unsigned)(lmin >> 32);
    const unsigned icur = (unsigned)(lmin & 0xFFFFFFFFull);
    unsigned vm = vcur;
    vm = dpp_min_u32<0x111>(vm); vm = dpp_min_u32<0x112>(vm);
    vm = dpp_min_u32<0x114>(vm); vm = dpp_min_u32<0x118>(vm);
    vm = dpp_min_u32<0x142>(vm); vm = dpp_min_u32<0x143>(vm);
    const unsigned vmin =
        (unsigned)__builtin_amdgcn_readlane((int)vm, 63);
    unsigned ic = (vcur == vmin) ? icur : 0xFFFFFFFFu;
    ic = dpp_min_u32<0x111>(ic); ic = dpp_min_u32<0x112>(ic);
    ic = dpp_min_u32<0x114>(ic); ic = dpp_min_u32<0x118>(ic);
    ic = dpp_min_u32<0x142>(ic); ic = dpp_min_u32<0x143>(ic);
    const unsigned imin =
        (unsigned)__builtin_amdgcn_readlane((int)ic, 63);

    if (lane == 0)
      wred[j & 1][wave] =
          ((unsigned long long)vmin << 32) | (unsigned long long)imin;
    __syncthreads();
    unsigned long long w = wred[j & 1][0];
    for (int q2 = 1; q2 < 4; ++q2) {
      const unsigned long long o = wred[j & 1][q2];
      w = w < o ? w : o;
    }
    const int widx = (int)(unsigned)(w & 0xFFFFFFFFull);
    if (tid == (widx & 255)) {  // owner removes winner, rebuilds local min
      for (int s = 0; s < 32; ++s)
        if ((unsigned)(keys[s] & 0xFFFFFFFFull) == (unsigned)widx)
          keys[s] = ~0ull;
      lmin = keys[0];
      for (int s = 1; s < 32; ++s) lmin = lmin < keys[s] ? lmin : keys[s];
    }
    if (tid == 0) knn_sh[j] = widx;
  }
  __syncthreads();

  // gather + center-relative xyz; 192 output floats per group
  float* outg = grouped + ((size_t)b * NGRP + g) * GSZ * NCH;
  for (int t = tid; t < GSZ * NCH; t += 256) {
    const int n = t / 6, c = t % 6;
    const int idx = knn_sh[n];
    float v = P[idx * 6 + c];
    if (c < 3) v = v - cen[c];  // exact ref subtract
    outg[t] = v;
  }
}

extern "C" void kernel_launch(void* const* d_in, const int* in_sizes, int n_in,
                              void* d_out, int out_size, void* d_ws, size_t ws_size,
                              hipStream_t stream) {
  const float* points = (const float*)d_in[0];
  float* out = (float*)d_out;
  float* grouped = out;                                        // [16,512,32,6]
  float* centers = out + (size_t)BATCH * NGRP * GSZ * NCH;     // [16,512,3]

  fps_kernel<<<BATCH, FPS_T, 0, stream>>>(points, centers);
  knn_kernel<<<dim3(NGRP, BATCH), 256, 0, stream>>>(points, centers, grouped);
}